// Round 3
// baseline (304.299 us; speedup 1.0000x reference)
//
#include <hip/hip_runtime.h>
#include <math.h>

// Problem constants (from reference): S=7, NB=2, C=20
#define SS 7
#define CC 20
#define CELL_PRED 30            // C + NB*5
#define CELL_TGT  25            // C + 1 + 4
#define TILE 128                // cells per tile
#define BLOCK 128               // threads per block (2 waves)
#define P4_PER_TILE (TILE * CELL_PRED / 4)   // 960 float4 per tile
#define T4_PER_TILE (TILE * CELL_TGT / 4)    // 800 float4 per tile
#define NPJ 8                   // ceil(960/128); j=7 active for tid<64
#define NTJ 7                   // ceil(800/128); j=6 active for tid<32
#define GRID 1280               // 5 blocks/CU (LDS-bound: 28.2KB -> 5/CU), persistent
// R1/R2 lesson: 12544 one-shot waves complete at a fixed ~165 waves/us
// regardless of occupancy or data residency (L3-warm replays identical) ->
// per-WG dispatch/alloc churn + serial load->vmcnt(0)->die chain is the
// limiter, NOT memory. Persistent blocks + register-prefetch pipelining.

__device__ __forceinline__ float iou_box(const float* __restrict__ a,
                                         const float* __restrict__ b) {
    const float EPS = 1e-6f;
    float ax1 = a[0] - a[2] * 0.5f, ay1 = a[1] - a[3] * 0.5f;
    float ax2 = a[0] + a[2] * 0.5f, ay2 = a[1] + a[3] * 0.5f;
    float bx1 = b[0] - b[2] * 0.5f, by1 = b[1] - b[3] * 0.5f;
    float bx2 = b[0] + b[2] * 0.5f, by2 = b[1] + b[3] * 0.5f;
    float iw = fmaxf(fminf(ax2, bx2) - fmaxf(ax1, bx1), 0.0f);
    float ih = fmaxf(fminf(ay2, by2) - fmaxf(ay1, by1), 0.0f);
    float inter = iw * ih;
    float area_a = fabsf((ax2 - ax1) * (ay2 - ay1));
    float area_b = fabsf((bx2 - bx1) * (by2 - by1));
    return inter / (area_a + area_b - inter + EPS);
}

__global__ __launch_bounds__(BLOCK) void yolo_loss_fused(
    const float* __restrict__ pred,   // [nCells * 30]
    const float* __restrict__ tgt,    // [nCells * 25]
    float* __restrict__ out,          // [1]
    double* __restrict__ accum,       // d_ws+0: double sum (memset 0)
    int* __restrict__ counter,        // d_ws+8: int arrival count (memset 0)
    int nCells, int nTiles, double invN)
{
    __shared__ __align__(16) float s_pred[TILE * CELL_PRED]; // 15360 B
    __shared__ __align__(16) float s_tgt [TILE * CELL_TGT];  // 12800 B
    __shared__ float s_red[2];

    const int tid = threadIdx.x;

    float4 rp[NPJ], rt[NTJ];

    // ---- prefetch first tile into registers (coalesced float4) ----
    int t = blockIdx.x;
    {
        const float4* gp = (const float4*)pred + (size_t)t * P4_PER_TILE;
        const float4* gt = (const float4*)tgt + (size_t)t * T4_PER_TILE;
        #pragma unroll
        for (int j = 0; j < NPJ; ++j) {
            int idx = tid + j * BLOCK;
            if (idx < P4_PER_TILE) rp[j] = gp[idx];
        }
        #pragma unroll
        for (int j = 0; j < NTJ; ++j) {
            int idx = tid + j * BLOCK;
            if (idx < T4_PER_TILE) rt[j] = gt[idx];
        }
    }

    float loss = 0.0f;

    while (t < nTiles) {
        __syncthreads();   // previous tile's compute done -> LDS reusable
        // ---- registers -> LDS ----
        {
            float4* sp = (float4*)s_pred;
            float4* st = (float4*)s_tgt;
            #pragma unroll
            for (int j = 0; j < NPJ; ++j) {
                int idx = tid + j * BLOCK;
                if (idx < P4_PER_TILE) sp[idx] = rp[j];
            }
            #pragma unroll
            for (int j = 0; j < NTJ; ++j) {
                int idx = tid + j * BLOCK;
                if (idx < T4_PER_TILE) st[idx] = rt[j];
            }
        }
        __syncthreads();

        // ---- issue next tile's loads NOW; they fly during compute ----
        int tn = t + GRID;
        if (tn < nTiles) {
            const float4* gp = (const float4*)pred + (size_t)tn * P4_PER_TILE;
            const float4* gt = (const float4*)tgt + (size_t)tn * T4_PER_TILE;
            #pragma unroll
            for (int j = 0; j < NPJ; ++j) {
                int idx = tid + j * BLOCK;
                if (idx < P4_PER_TILE) rp[j] = gp[idx];
            }
            #pragma unroll
            for (int j = 0; j < NTJ; ++j) {
                int idx = tid + j * BLOCK;
                if (idx < T4_PER_TILE) rt[j] = gt[idx];
            }
        }

        // ---- compute this tile: one cell per thread ----
        {
            const float* p = s_pred + tid * CELL_PRED;
            const float* tt = s_tgt + tid * CELL_TGT;
            const float* b1 = p + CC;
            const float* b2 = p + CC + 5;
            const float* tb = tt + CC;

            float obj = (tb[0] == 1.0f) ? 1.0f : 0.0f;

            float iou1 = iou_box(b1, tb);
            float iou2 = iou_box(b2, tb);
            bool pick1 = iou1 > iou2;
            float r0 = pick1 ? b1[0] : b2[0];
            float r1 = pick1 ? b1[1] : b2[1];
            float r2 = pick1 ? b1[2] : b2[2];
            float r3 = pick1 ? b1[3] : b2[3];
            float r4 = pick1 ? b1[4] : b2[4];

            float dx = r0 - tb[0], dy = r1 - tb[1];
            float xy = dx * dx + dy * dy;
            float dw = sqrtf(r2) - sqrtf(tb[2]);
            float dh = sqrtf(r3) - sqrtf(tb[3]);
            float wh = dw * dw + dh * dh;
            float coord = 5.0f * (xy + wh);
            float dconf = r4 - tb[4];
            float conf = dconf * dconf;

            float cls = 0.0f;
            #pragma unroll
            for (int k = 0; k < CC; ++k) {
                float d = p[k] - tt[k];
                cls += d * d;
            }

            float noobj = 0.5f * (1.0f - obj) * (b1[4] * b1[4] + b2[4] * b2[4]);
            loss += obj * (coord + conf + cls) + noobj;
        }
        t = tn;
    }

    // ---- block reduction: wave butterfly, then 2 waves via LDS ----
    #pragma unroll
    for (int off = 32; off > 0; off >>= 1)
        loss += __shfl_down(loss, off, 64);
    __syncthreads();                 // s_pred reads done before s_red reuse
    if ((tid & 63) == 0) s_red[tid >> 6] = loss;
    __syncthreads();

    // ---- fused final reduce: double atomic + last-block-done ----
    if (tid == 0) {
        double part = (double)s_red[0] + (double)s_red[1];
        atomicAdd(accum, part);
        __threadfence();             // sum visible before arrival
        int old = atomicAdd(counter, 1);
        if (old == GRID - 1) {
            double total = atomicAdd(accum, 0.0);  // atomic read, device scope
            out[0] = (float)(total * invN);
        }
    }
}

extern "C" void kernel_launch(void* const* d_in, const int* in_sizes, int n_in,
                              void* d_out, int out_size, void* d_ws, size_t ws_size,
                              hipStream_t stream) {
    const float* pred = (const float*)d_in[0];
    const float* tgt  = (const float*)d_in[1];
    float* out = (float*)d_out;
    double* accum = (double*)d_ws;
    int* counter = (int*)((char*)d_ws + 8);

    const int N = in_sizes[0] / (SS * SS * CELL_PRED);   // 16384
    const int nCells = N * SS * SS;                      // 802816 (divisible by TILE)
    const int nTiles = nCells / TILE;                    // 6272

    hipMemsetAsync(d_ws, 0, 16, stream);                 // zero accum + counter
    yolo_loss_fused<<<GRID, BLOCK, 0, stream>>>(
        pred, tgt, out, accum, counter, nCells, nTiles, 1.0 / (double)N);
}

// Round 4
// 232.512 us; speedup vs baseline: 1.3087x; 1.3087x over previous
//
#include <hip/hip_runtime.h>
#include <math.h>

// Problem constants (from reference): S=7, NB=2, C=20
#define SS 7
#define CC 20
#define CELL_PRED 30            // C + NB*5
#define CELL_TGT  25            // C + 1 + 4
#define TILE 128                // cells per tile
#define BLOCK 128               // threads per block (2 waves)
#define P4_PER_TILE (TILE * CELL_PRED / 4)   // 960 float4
#define T4_PER_TILE (TILE * CELL_TGT / 4)    // 800 float4
#define NPJ 8                   // ceil(960/128)
#define NTJ 7                   // ceil(800/128)
#define GRID 1280               // 5 blocks/CU (LDS 28.2KB), persistent
// R3 lesson: register double-buffer arrays living across __syncthreads were
// spilled to scratch (WRITE_SIZE 0.4MB -> 172.5MB == full input size) ->
// kernel became BW-bound on its own spill traffic. This version keeps NOTHING
// in registers across barriers except the scalar loss accumulator; latency
// hiding is cross-block (5 persistent blocks/CU interleave load/compute).

__device__ __forceinline__ float iou_box(const float* __restrict__ a,
                                         const float* __restrict__ b) {
    const float EPS = 1e-6f;
    float ax1 = a[0] - a[2] * 0.5f, ay1 = a[1] - a[3] * 0.5f;
    float ax2 = a[0] + a[2] * 0.5f, ay2 = a[1] + a[3] * 0.5f;
    float bx1 = b[0] - b[2] * 0.5f, by1 = b[1] - b[3] * 0.5f;
    float bx2 = b[0] + b[2] * 0.5f, by2 = b[1] + b[3] * 0.5f;
    float iw = fmaxf(fminf(ax2, bx2) - fmaxf(ax1, bx1), 0.0f);
    float ih = fmaxf(fminf(ay2, by2) - fmaxf(ay1, by1), 0.0f);
    float inter = iw * ih;
    float area_a = fabsf((ax2 - ax1) * (ay2 - ay1));
    float area_b = fabsf((bx2 - bx1) * (by2 - by1));
    return inter / (area_a + area_b - inter + EPS);
}

__global__ __launch_bounds__(BLOCK) void yolo_loss_fused(
    const float* __restrict__ pred,   // [nCells * 30]
    const float* __restrict__ tgt,    // [nCells * 25]
    float* __restrict__ out,          // [1]
    double* __restrict__ accum,       // d_ws+0: double sum (memset 0)
    int* __restrict__ counter,        // d_ws+8: int arrival count (memset 0)
    int nTiles, double invN)
{
    __shared__ __align__(16) float s_pred[TILE * CELL_PRED]; // 15360 B
    __shared__ __align__(16) float s_tgt [TILE * CELL_TGT];  // 12800 B
    __shared__ float s_red[2];

    const int tid = threadIdx.x;
    float loss = 0.0f;

    for (int t = blockIdx.x; t < nTiles; t += GRID) {
        __syncthreads();   // previous tile's LDS reads complete before overwrite

        // ---- synchronous coalesced float4 staging into LDS ----
        {
            const float4* gp = (const float4*)pred + (size_t)t * P4_PER_TILE;
            const float4* gt = (const float4*)tgt + (size_t)t * T4_PER_TILE;
            float4* sp = (float4*)s_pred;
            float4* st = (float4*)s_tgt;
            #pragma unroll
            for (int j = 0; j < NPJ; ++j) {
                int idx = tid + j * BLOCK;
                if (idx < P4_PER_TILE) sp[idx] = gp[idx];
            }
            #pragma unroll
            for (int j = 0; j < NTJ; ++j) {
                int idx = tid + j * BLOCK;
                if (idx < T4_PER_TILE) st[idx] = gt[idx];
            }
        }
        __syncthreads();

        // ---- compute this tile: one cell per thread ----
        {
            const float* p  = s_pred + tid * CELL_PRED;
            const float* tt = s_tgt  + tid * CELL_TGT;
            const float* b1 = p + CC;
            const float* b2 = p + CC + 5;
            const float* tb = tt + CC;

            float obj = (tb[0] == 1.0f) ? 1.0f : 0.0f;

            float iou1 = iou_box(b1, tb);
            float iou2 = iou_box(b2, tb);
            bool pick1 = iou1 > iou2;
            float r0 = pick1 ? b1[0] : b2[0];
            float r1 = pick1 ? b1[1] : b2[1];
            float r2 = pick1 ? b1[2] : b2[2];
            float r3 = pick1 ? b1[3] : b2[3];
            float r4 = pick1 ? b1[4] : b2[4];

            float dx = r0 - tb[0], dy = r1 - tb[1];
            float xy = dx * dx + dy * dy;
            float dw = sqrtf(r2) - sqrtf(tb[2]);
            float dh = sqrtf(r3) - sqrtf(tb[3]);
            float wh = dw * dw + dh * dh;
            float coord = 5.0f * (xy + wh);
            float dconf = r4 - tb[4];
            float conf = dconf * dconf;

            float cls = 0.0f;
            #pragma unroll
            for (int k = 0; k < CC; ++k) {
                float d = p[k] - tt[k];
                cls += d * d;
            }

            float noobj = 0.5f * (1.0f - obj) * (b1[4] * b1[4] + b2[4] * b2[4]);
            loss += obj * (coord + conf + cls) + noobj;
        }
    }

    // ---- block reduction: wave butterfly, then 2 waves via LDS ----
    #pragma unroll
    for (int off = 32; off > 0; off >>= 1)
        loss += __shfl_down(loss, off, 64);
    __syncthreads();
    if ((tid & 63) == 0) s_red[tid >> 6] = loss;
    __syncthreads();

    // ---- fused final reduce: double atomic + last-block-done ----
    if (tid == 0) {
        double part = (double)s_red[0] + (double)s_red[1];
        atomicAdd(accum, part);
        __threadfence();             // sum visible before arrival
        int old = atomicAdd(counter, 1);
        if (old == GRID - 1) {
            double total = atomicAdd(accum, 0.0);  // device-scope atomic read
            out[0] = (float)(total * invN);
        }
    }
}

extern "C" void kernel_launch(void* const* d_in, const int* in_sizes, int n_in,
                              void* d_out, int out_size, void* d_ws, size_t ws_size,
                              hipStream_t stream) {
    const float* pred = (const float*)d_in[0];
    const float* tgt  = (const float*)d_in[1];
    float* out = (float*)d_out;
    double* accum = (double*)d_ws;
    int* counter = (int*)((char*)d_ws + 8);

    const int N = in_sizes[0] / (SS * SS * CELL_PRED);   // 16384
    const int nCells = N * SS * SS;                      // 802816 (divisible by TILE)
    const int nTiles = nCells / TILE;                    // 6272

    hipMemsetAsync(d_ws, 0, 16, stream);                 // zero accum + counter
    yolo_loss_fused<<<GRID, BLOCK, 0, stream>>>(
        pred, tgt, out, accum, counter, nTiles, 1.0 / (double)N);
}